// Round 10
// baseline (434.583 us; speedup 1.0000x reference)
//
#include <hip/hip_runtime.h>

#define T_SEQ 4096
#define D_MODEL 768
#define N_HEADS 12
#define HEAD_DIM 64
#define FF_DIM 3072
#define QKV_LD 2304   // 3*D_MODEL
#define AG_LD  6144   // 2*FF_DIM
#define CHUNK 16      // k-tiles per attention block
#define MAXC 4        // max chunks per q-tile (64/16)
#define PSTRIDE 4160  // 64*64 + 64 floats per partial

typedef __bf16 bf16x8 __attribute__((ext_vector_type(8)));
typedef float  f32x4  __attribute__((ext_vector_type(4)));

__device__ __forceinline__ unsigned short f2bf(float f) {
    unsigned int u = __float_as_uint(f);
    u += 0x7FFFu + ((u >> 16) & 1u);
    return (unsigned short)(u >> 16);
}
__device__ __forceinline__ float bf2f(unsigned short s) {
    return __uint_as_float(((unsigned int)s) << 16);
}
__device__ __forceinline__ f32x4 mfma16(bf16x8 a, bf16x8 b, f32x4 c) {
    return __builtin_amdgcn_mfma_f32_16x16x32_bf16(a, b, c, 0, 0, 0);
}
// async global->LDS, 16B per lane; LDS dest = wave-uniform base + lane*16
__device__ __forceinline__ void gload_lds16(const unsigned short* g, unsigned short* l) {
    __builtin_amdgcn_global_load_lds(
        (const __attribute__((address_space(1))) unsigned int*)g,
        (__attribute__((address_space(3))) unsigned int*)l,
        16, 0, 0);
}

// ---------------------------------------------------------------------------
// Fused weight prep: all 7 transposes in one launch. Job table:
//  0..3 : 768x768  ilv=0  (Wq,Wk,Wv -> Wqkv_t @0/768/1536; Wo -> Wo_t @0)
//  4..5 : 768x3072 ilv=1  (w1 -> W12_t off0, w2 -> W12_t off16)
//  6    : 3072x768 ilv=0  (w3 -> W3_t)
// ---------------------------------------------------------------------------
__global__ __launch_bounds__(256) void weight_prep(const float* __restrict__ Wq,
                                                   const float* __restrict__ Wk,
                                                   const float* __restrict__ Wv,
                                                   const float* __restrict__ Wo,
                                                   const float* __restrict__ w1,
                                                   const float* __restrict__ w2,
                                                   const float* __restrict__ w3,
                                                   unsigned short* __restrict__ Wqkv_t,
                                                   unsigned short* __restrict__ Wo_t,
                                                   unsigned short* __restrict__ W12_t,
                                                   unsigned short* __restrict__ W3_t) {
    __shared__ float tile[32][33];
    const int b = blockIdx.x;
    const float* W; unsigned short* Wt;
    int K, N, off, ilv, bx, by;
    if (b < 2304) {                       // jobs 0-3: 576 blocks each (24x24)
        const int j = b / 576, lb = b % 576;
        bx = lb % 24; by = lb / 24;
        K = 768; N = 768; ilv = 0;
        if (j == 0)      { W = Wq; Wt = Wqkv_t; off = 0; }
        else if (j == 1) { W = Wk; Wt = Wqkv_t; off = 768; }
        else if (j == 2) { W = Wv; Wt = Wqkv_t; off = 1536; }
        else             { W = Wo; Wt = Wo_t;   off = 0; }
    } else if (b < 6912) {                // jobs 4-5: 2304 blocks each (96x24)
        const int j = (b - 2304) / 2304, lb = (b - 2304) % 2304;
        bx = lb % 96; by = lb / 96;
        K = 768; N = 3072; ilv = 1;
        W = j ? w2 : w1; Wt = W12_t; off = j ? 16 : 0;
    } else {                              // job 6: 2304 blocks (24x96)
        const int lb = b - 6912;
        bx = lb % 24; by = lb / 24;
        K = 3072; N = 768; ilv = 0;
        W = w3; Wt = W3_t; off = 0;
    }

    const int tx = threadIdx.x & 31, ty = threadIdx.x >> 5;  // 32 x 8
    const int n0 = bx * 32, k0 = by * 32;
    #pragma unroll
    for (int s = 0; s < 32; s += 8)
        tile[ty + s][tx] = W[(size_t)(k0 + ty + s) * N + n0 + tx];
    __syncthreads();
    #pragma unroll
    for (int s = 0; s < 32; s += 8) {
        const int nn = n0 + ty + s;
        const int R = ilv ? ((nn >> 4) * 32 + off + (nn & 15)) : (off + nn);
        Wt[(size_t)R * K + k0 + tx] = f2bf(tile[tx][ty + s]);
    }
}

// interleaved bias pack: o[(n>>4)*32 + (n&15)] = b1[n]; +16 -> b2[n]
__global__ __launch_bounds__(256) void packb12_kernel(const float* __restrict__ b1,
                                                      const float* __restrict__ b2,
                                                      float* __restrict__ o) {
    const int n = blockIdx.x * 256 + threadIdx.x;
    if (n < FF_DIM) {
        o[(n >> 4) * 32 + (n & 15)] = b1[n];
        o[(n >> 4) * 32 + 16 + (n & 15)] = b2[n];
    }
}

// ---------------------------------------------------------------------------
// V transpose (bf16) with per-64-tile KEY-SLOT PERMUTATION:
// Vt[c][t0 + s] = qkv[t0 + kl(s)][1536+c],  kl(s) = (s&3)*16 + (s>>2).
// This matches the P slot assignment s = 4r + ni in softmax_step, so the
// PV MFMA sums over a permuted (but consistent) key order.
// ---------------------------------------------------------------------------
__global__ __launch_bounds__(256) void vtrans_kernel(const unsigned short* __restrict__ qkv,
                                                     unsigned short* __restrict__ Vt) {
    __shared__ unsigned short tile[64][72];
    const int t0 = blockIdx.x * 64;   // seq
    const int c0 = blockIdx.y * 64;   // feature
    const int tr = threadIdx.x >> 3;         // 0..31
    const int tc = (threadIdx.x & 7) * 8;    // 0,8,..,56
    #pragma unroll
    for (int s = 0; s < 2; ++s) {
        uint4 v = *(const uint4*)(qkv + (size_t)(t0 + tr + s * 32) * QKV_LD + 2 * D_MODEL + c0 + tc);
        *(uint4*)(&tile[tr + s * 32][tc]) = v;
    }
    __syncthreads();
    #pragma unroll
    for (int sb = 0; sb < 2; ++sb) {
        const int cr = tr + sb * 32;
        unsigned short ob[8];
        #pragma unroll
        for (int j = 0; j < 8; ++j) {
            const int s = tc + j;
            ob[j] = tile[(s & 3) * 16 + (s >> 2)][cr];
        }
        *(uint4*)(Vt + (size_t)(c0 + cr) * T_SEQ + t0 + tc) = *(uint4*)ob;
    }
}

// ---------------------------------------------------------------------------
// LayerNorm (fp32 in, bf16 out)
// ---------------------------------------------------------------------------
__global__ __launch_bounds__(256) void ln_kernel(const float* __restrict__ x,
                                                 const float* __restrict__ g,
                                                 const float* __restrict__ b,
                                                 unsigned short* __restrict__ o) {
    const int row = blockIdx.x;
    const float* xr = x + (size_t)row * D_MODEL;
    unsigned short* orow = o + (size_t)row * D_MODEL;
    const int tid = threadIdx.x;

    float v0 = xr[tid], v1 = xr[tid + 256], v2 = xr[tid + 512];
    float sum = v0 + v1 + v2;

    __shared__ float red[4];
    __shared__ float mv[2];
    const int lane = tid & 63, wv = tid >> 6;

    #pragma unroll
    for (int off = 32; off > 0; off >>= 1) sum += __shfl_down(sum, off, 64);
    if (lane == 0) red[wv] = sum;
    __syncthreads();
    if (tid == 0) mv[0] = (red[0] + red[1] + red[2] + red[3]) * (1.0f / D_MODEL);
    __syncthreads();
    const float mean = mv[0];

    float d0 = v0 - mean, d1 = v1 - mean, d2 = v2 - mean;
    float sq = d0 * d0 + d1 * d1 + d2 * d2;
    #pragma unroll
    for (int off = 32; off > 0; off >>= 1) sq += __shfl_down(sq, off, 64);
    if (lane == 0) red[wv] = sq;
    __syncthreads();
    if (tid == 0) mv[1] = (red[0] + red[1] + red[2] + red[3]) * (1.0f / D_MODEL);
    __syncthreads();
    const float rs = rsqrtf(mv[1] + 1e-5f);

    orow[tid]       = f2bf(g[tid]       * d0 * rs + b[tid]);
    orow[tid + 256] = f2bf(g[tid + 256] * d1 * rs + b[tid + 256]);
    orow[tid + 512] = f2bf(g[tid + 512] * d2 * rs + b[tid + 512]);
}

// ---------------------------------------------------------------------------
// bf16 MFMA GEMM, templated tile. BM=WY*MI*16, BN=WX*NI*16, BK=32, 256 thr,
// async global_load_lds staging, double-buffered, one barrier per iter.
// Chunk c (16B) holds X[(c>>6)*16 + (c&15)][((c>>4)&3)*8..+8].
// EPI=0: C = acc + bias + res -> Cf (fp32) or Cb (bf16), pitch N.
// EPI=1: SwiGLU epilogue on 16-col-interleaved B: u = silu(a+ba)*(g+bg),
//        -> Cb, pitch N/2.
// ---------------------------------------------------------------------------
template<int BM, int BN, int WY, int WX, int MI, int NI, int EPI>
__global__ __launch_bounds__(256) void mfma_gemm(const unsigned short* __restrict__ A,
                                                 const unsigned short* __restrict__ Bt,
                                                 const float* __restrict__ bias,
                                                 const float* __restrict__ res,
                                                 float* __restrict__ Cf,
                                                 unsigned short* __restrict__ Cb,
                                                 int M, int N, int K) {
    constexpr int CA = BM * 4;            // A chunks
    constexpr int CT = BM * 4 + BN * 4;   // total chunks
    constexpr int SA = CA / 256;          // DMA steps covering A
    constexpr int ST = CT / 256;          // total DMA steps
    __shared__ unsigned short S[2][CT * 8];

    const int t = threadIdx.x;
    const int bn = blockIdx.x * BN;
    const int bm = blockIdx.y * BM;
    const int w = t >> 6, lane = t & 63;
    const int wy = w / WX, wx = w % WX;
    const int quad = lane >> 4, r = lane & 15;
    const int rc = lane & 15, kq = (lane >> 4) & 3;

    const unsigned short* gp[ST];
    #pragma unroll
    for (int s = 0; s < ST; ++s) {
        if (s < SA) gp[s] = A  + (size_t)(bm + (s * 4 + w) * 16 + rc) * K + kq * 8;
        else        gp[s] = Bt + (size_t)(bn + ((s - SA) * 4 + w) * 16 + rc) * K + kq * 8;
    }

    f32x4 acc[MI][NI];
    const f32x4 fz = {0.f, 0.f, 0.f, 0.f};
    #pragma unroll
    for (int i = 0; i < MI; ++i)
        #pragma unroll
        for (int j = 0; j < NI; ++j) acc[i][j] = fz;

    // prologue: stage k-block 0 into buf 0
    #pragma unroll
    for (int s = 0; s < ST; ++s)
        gload_lds16(gp[s], &S[0][(s * 256 + w * 64) * 8]);

    const int niter = K >> 5;
    for (int it = 0; it < niter; ++it) {
        const int buf = it & 1;
        __syncthreads();            // drains vmcnt: buf's DMA complete; prior reads done
        if (it + 1 < niter) {
            const int ko = (it + 1) * 32;
            #pragma unroll
            for (int s = 0; s < ST; ++s)
                gload_lds16(gp[s] + ko, &S[buf ^ 1][(s * 256 + w * 64) * 8]);
        }

        bf16x8 af[MI], bfr[NI];
        #pragma unroll
        for (int mi = 0; mi < MI; ++mi)
            af[mi] = *(const bf16x8*)(&S[buf][((wy * MI + mi) * 64 + lane) * 8]);
        #pragma unroll
        for (int ni = 0; ni < NI; ++ni)
            bfr[ni] = *(const bf16x8*)(&S[buf][(CA + (wx * NI + ni) * 64 + lane) * 8]);
        #pragma unroll
        for (int mi = 0; mi < MI; ++mi)
            #pragma unroll
            for (int ni = 0; ni < NI; ++ni)
                acc[mi][ni] = mfma16(af[mi], bfr[ni], acc[mi][ni]);
    }

    float bv[NI];
    #pragma unroll
    for (int ni = 0; ni < NI; ++ni)
        bv[ni] = bias ? bias[bn + (wx * NI + ni) * 16 + r] : 0.0f;

    if (EPI == 0) {
        #pragma unroll
        for (int mi = 0; mi < MI; ++mi) {
            #pragma unroll
            for (int i = 0; i < 4; ++i) {
                const int m = bm + (wy * MI + mi) * 16 + quad * 4 + i;
                #pragma unroll
                for (int ni = 0; ni < NI; ++ni) {
                    const int n = bn + (wx * NI + ni) * 16 + r;
                    float v = acc[mi][ni][i] + bv[ni];
                    if (res) v += res[(size_t)m * N + n];
                    if (Cf) Cf[(size_t)m * N + n] = v;
                    else    Cb[(size_t)m * N + n] = f2bf(v);
                }
            }
        }
    } else {
        // SwiGLU: ni pairs (2p, 2p+1) = (a-block, g-block), same lane r
        #pragma unroll
        for (int mi = 0; mi < MI; ++mi) {
            #pragma unroll
            for (int i = 0; i < 4; ++i) {
                const int m = bm + (wy * MI + mi) * 16 + quad * 4 + i;
                #pragma unroll
                for (int p = 0; p < NI / 2; ++p) {
                    float a = acc[mi][2 * p][i] + bv[2 * p];
                    float g = acc[mi][2 * p + 1][i] + bv[2 * p + 1];
                    float uu = a / (1.0f + __expf(-a)) * g;
                    const int n = (bn >> 1) + wx * (NI / 2) * 16 + p * 16 + r;
                    Cb[(size_t)m * (N >> 1) + n] = f2bf(uu);
                }
            }
        }
    }
}

// ---------------------------------------------------------------------------
// Softmax step, fixed-max: p = exp(s) (scale folded into Q), masked -> 0.
// P written in key-slot order s = 4r + ni: the 4 values per (lane, row) are
// consecutive shorts -> ONE b64 write (vs 16 b16). V is staged with the
// matching kl(s) = (s&3)*16 + (s>>2) permutation (vtrans), so PV is exact.
// ---------------------------------------------------------------------------
template <bool DIAG>
__device__ __forceinline__ void softmax_step(const f32x4 sacc[4],
                                             unsigned short* __restrict__ Pw,
                                             int k0, int qg_base, int r, int quad) {
    #pragma unroll
    for (int i = 0; i < 4; ++i) {
        unsigned int pk[2];
        #pragma unroll
        for (int ni = 0; ni < 4; ++ni) {
            float p = __expf(sacc[ni][i]);
            if (DIAG) { if (k0 + ni * 16 + r > qg_base + i) p = 0.0f; }
            const unsigned int pb = (__float_as_uint(p) + 0x8000u) >> 16;  // fast RN
            if (ni & 1) pk[ni >> 1] |= pb << 16;
            else        pk[ni >> 1] = pb;
        }
        // slot s = 4r + ni -> shorts at ((r>>3)*64 + ((r&7)>>1)*16 + quad*4+i)*8 + 4*(r&1)
        uint2 w; w.x = pk[0]; w.y = pk[1];
        *(uint2*)(&Pw[(((r >> 3) * 64 + ((r & 7) >> 1) * 16 + quad * 4 + i) * 8 + 4 * (r & 1))]) = w;
    }
}

// ---------------------------------------------------------------------------
// Flash attention partial, bf16 MFMA, fixed-max softmax, K-SPLIT.
// Block = (64 q-rows, head, k-chunk of <=16 k-tiles). Partial O (fp32 64x64)
// and l (fp32 64) per chunk to workspace; additive across chunks.
// ---------------------------------------------------------------------------
__global__ __launch_bounds__(256) void attn_partial(const unsigned short* __restrict__ qkv,
                                                    const unsigned short* __restrict__ Vt,
                                                    float* __restrict__ part) {
    const int h = blockIdx.y;
    // decode blockIdx.x -> (qt, ci), longest q-tiles first
    int b = (int)blockIdx.x, qt = 63, ci = 0;
    for (int q = 63; q >= 0; --q) {
        const int nc = (q >> 4) + 1;       // ceil((q+1)/16)
        if (b < nc) { qt = q; ci = b; break; }
        b -= nc;
    }
    const int q0 = qt * 64;
    const int kb = ci * CHUNK;             // first k-tile of this chunk
    const int nt = min(CHUNK, qt + 1 - kb);

    const int t = threadIdx.x;
    const int w = t >> 6, lane = t & 63;
    const int quad = lane >> 4, r = lane & 15;

    __shared__ unsigned short Ks[2][4096];
    __shared__ unsigned short Vs[2][4096];
    __shared__ unsigned short Ps[4][1024];

    // Q fragments, scale 1/8 folded in (exact power of 2)
    bf16x8 aq[2];
    {
        const unsigned short* qp = qkv + (size_t)(q0 + w * 16 + r) * QKV_LD + h * 64 + quad * 8;
        uint4 q0v = *(const uint4*)(qp);
        uint4 q1v = *(const uint4*)(qp + 32);
        const unsigned short* p0 = (const unsigned short*)&q0v;
        const unsigned short* p1 = (const unsigned short*)&q1v;
        #pragma unroll
        for (int j = 0; j < 8; ++j) {
            aq[0][j] = (__bf16)(bf2f(p0[j]) * 0.125f);
            aq[1][j] = (__bf16)(bf2f(p1[j]) * 0.125f);
        }
    }

    bf16x8 ones;
    #pragma unroll
    for (int j = 0; j < 8; ++j) ones[j] = (__bf16)1.0f;

    // per-lane staging sources (chunk c = s*256 + w*64 + lane), offset by kb
    const int rc = lane & 15, qc = (lane >> 4) & 3;
    const unsigned short* kg0 = qkv + (size_t)(kb * 64 + w * 16 + rc) * QKV_LD + D_MODEL + h * 64 + qc * 8;
    const unsigned short* kg1 = kg0 + 32;
    const unsigned short* vg0 = Vt + (size_t)(h * 64 + w * 16 + rc) * T_SEQ + kb * 64 + qc * 8;
    const unsigned short* vg1 = vg0 + 32;
    const int l0 = (w * 64) * 8, l1 = (256 + w * 64) * 8;

    const f32x4 fz = {0.f, 0.f, 0.f, 0.f};
    f32x4 acc_o[4] = {fz, fz, fz, fz};
    f32x4 acc_l = fz;
    const int qg_base = q0 + w * 16 + quad * 4;

    // prologue: stage first tile into buf 0
    gload_lds16(kg0, &Ks[0][l0]);
    gload_lds16(kg1, &Ks[0][l1]);
    gload_lds16(vg0, &Vs[0][l0]);
    gload_lds16(vg1, &Vs[0][l1]);

    for (int lt = 0; lt < nt; ++lt) {
        const int kt = kb + lt;
        const int buf = lt & 1;
        __syncthreads();            // DMA for buf complete; prior reads done
        if (lt + 1 < nt) {
            const size_t kofs = (size_t)(lt + 1) * 64;
            gload_lds16(kg0 + kofs * QKV_LD, &Ks[buf ^ 1][l0]);
            gload_lds16(kg1 + kofs * QKV_LD, &Ks[buf ^ 1][l1]);
            gload_lds16(vg0 + kofs, &Vs[buf ^ 1][l0]);
            gload_lds16(vg1 + kofs, &Vs[buf ^ 1][l1]);
        }

        // S = (Q/8) @ K^T
        f32x4 sacc[4] = {fz, fz, fz, fz};
        #pragma unroll
        for (int ks = 0; ks < 2; ++ks)
            #pragma unroll
            for (int ni = 0; ni < 4; ++ni) {
                bf16x8 bk = *(const bf16x8*)(&Ks[buf][((ks * 4 + ni) * 64 + lane) * 8]);
                sacc[ni] = mfma16(aq[ks], bk, sacc[ni]);
            }

        const int k0 = kt * 64;
        if (kt == qt)
            softmax_step<true >(sacc, Ps[w], k0, qg_base, r, quad);
        else
            softmax_step<false>(sacc, Ps[w], k0, qg_base, r, quad);

        // O += P @ V ; l += P @ 1   (P per-wave; lgkm ordering suffices)
        #pragma unroll
        for (int ks = 0; ks < 2; ++ks) {
            bf16x8 ap = *(const bf16x8*)(&Ps[w][(ks * 64 + lane) * 8]);
            #pragma unroll
            for (int nd = 0; nd < 4; ++nd) {
                bf16x8 bv = *(const bf16x8*)(&Vs[buf][((ks * 4 + nd) * 64 + lane) * 8]);
                acc_o[nd] = mfma16(ap, bv, acc_o[nd]);
            }
            acc_l = mfma16(ap, ones, acc_l);
        }
    }

    // write fp32 partial: O[64][64] then l[64]
    float* pb = part + ((size_t)(qt * N_HEADS + h) * MAXC + ci) * PSTRIDE;
    #pragma unroll
    for (int i = 0; i < 4; ++i) {
        const int row = w * 16 + quad * 4 + i;
        #pragma unroll
        for (int nd = 0; nd < 4; ++nd)
            pb[row * 64 + nd * 16 + r] = acc_o[nd][i];
        if (r == 0) pb[4096 + row] = acc_l[i];   // all 16 cols of acc_l equal
    }
}

// ---------------------------------------------------------------------------
// Merge partials: ctx[q0+row][h*64+c] = (sum_ci O_ci[row][c]) / (sum_ci l_ci[row])
// ---------------------------------------------------------------------------
__global__ __launch_bounds__(256) void attn_merge(const float* __restrict__ part,
                                                  unsigned short* __restrict__ ctx) {
    const int qt = blockIdx.x, h = blockIdx.y;
    const int nc = (qt >> 4) + 1;
    const int t = threadIdx.x;
    const int row = t >> 2, cg = (t & 3) * 16;

    float o[16];
    #pragma unroll
    for (int j = 0; j < 16; ++j) o[j] = 0.0f;
    float l = 0.0f;

    for (int ci = 0; ci < nc; ++ci) {
        const float* pb = part + ((size_t)(qt * N_HEADS + h) * MAXC + ci) * PSTRIDE;
        l += pb[4096 + row];
        #pragma unroll
        for (int j = 0; j < 16; j += 4) {
            float4 v = *(const float4*)(pb + row * 64 + cg + j);
            o[j] += v.x; o[j + 1] += v.y; o[j + 2] += v.z; o[j + 3] += v.w;
        }
    }
    const float inv = 1.0f / l;
    unsigned short ob[16];
    #pragma unroll
    for (int j = 0; j < 16; ++j) ob[j] = f2bf(o[j] * inv);
    unsigned short* dst = ctx + (size_t)(qt * 64 + row) * D_MODEL + h * 64 + cg;
    *(uint4*)(dst) = *(uint4*)(ob);
    *(uint4*)(dst + 8) = *(uint4*)(ob + 8);
}

// ---------------------------------------------------------------------------
// launch
// ---------------------------------------------------------------------------
extern "C" void kernel_launch(void* const* d_in, const int* in_sizes, int n_in,
                              void* d_out, int out_size, void* d_ws, size_t ws_size,
                              hipStream_t stream) {
    const float* x  = (const float*)d_in[0];
    const float* Wq = (const float*)d_in[1];
    const float* Wk = (const float*)d_in[2];
    const float* Wv = (const float*)d_in[3];
    const float* Wo = (const float*)d_in[4];
    const float* bo = (const float*)d_in[5];
    const float* w1 = (const float*)d_in[6];
    const float* b1 = (const float*)d_in[7];
    const float* w2 = (const float*)d_in[8];
    const float* b2 = (const float*)d_in[9];
    const float* w3 = (const float*)d_in[10];
    const float* b3 = (const float*)d_in[11];
    const float* g1 = (const float*)d_in[12];
    const float* s1 = (const float*)d_in[13];
    const float* g2 = (const float*)d_in[14];
    const float* s2 = (const float*)d_in[15];
    float* out = (float*)d_out;

    const size_t TD = (size_t)T_SEQ * D_MODEL;

    char* p = (char*)d_ws;
    auto alloc = [&](size_t bytes) { char* r = p; p += (bytes + 255) & ~(size_t)255; return r; };
    unsigned short* h      = (unsigned short*)alloc(TD * 2);
    unsigned short* qkv    = (unsigned short*)alloc((size_t)T_SEQ * QKV_LD * 2);
    unsigned short* Vtb    = (unsigned short*)alloc((size_t)D_MODEL * T_SEQ * 2);
    unsigned short* ctx    = (unsigned short*)alloc(TD * 2);
    float*          x2     = (float*)alloc(TD * 4);
    unsigned short* h2     = (unsigned short*)alloc(TD * 2);
    unsigned short* u      = (unsigned short*)alloc((size_t)T_SEQ * FF_DIM * 2);
    unsigned short* Wqkv_t = (unsigned short*)alloc((size_t)QKV_LD * D_MODEL * 2);
    unsigned short* Wo_t   = (unsigned short*)alloc((size_t)D_MODEL * D_MODEL * 2);
    unsigned short* W12_t  = (unsigned short*)alloc((size_t)AG_LD * D_MODEL * 2);
    unsigned short* W3_t   = (unsigned short*)alloc((size_t)D_MODEL * FF_DIM * 2);
    float*          b12    = (float*)alloc((size_t)AG_LD * 4);
    float*          part   = (float*)alloc((size_t)64 * N_HEADS * MAXC * PSTRIDE * 4);

    // --- weight prep (single fused launch + bias pack) ---
    weight_prep<<<9216, 256, 0, stream>>>(Wq, Wk, Wv, Wo, w1, w2, w3,
                                          Wqkv_t, Wo_t, W12_t, W3_t);
    packb12_kernel<<<12, 256, 0, stream>>>(b1, b2, b12);

    // --- block ---
    ln_kernel<<<T_SEQ, 256, 0, stream>>>(x, g1, s1, h);

    // QKV: [T,768] @ [768,2304]
    mfma_gemm<128, 128, 2, 2, 4, 4, 0><<<dim3(QKV_LD / 128, T_SEQ / 128), 256, 0, stream>>>(
        h, Wqkv_t, nullptr, nullptr, nullptr, qkv, T_SEQ, QKV_LD, D_MODEL);

    vtrans_kernel<<<dim3(T_SEQ / 64, D_MODEL / 64), 256, 0, stream>>>(qkv, Vtb);

    // attention: 160 chunks/head, partials + merge
    attn_partial<<<dim3(160, N_HEADS), 256, 0, stream>>>(qkv, Vtb, part);
    attn_merge<<<dim3(T_SEQ / 64, N_HEADS), 256, 0, stream>>>(part, ctx);

    // Wo: [T,768] @ [768,768] + bo + x   (64x64 tile -> 768 blocks)
    mfma_gemm<64, 64, 2, 2, 2, 2, 0><<<dim3(D_MODEL / 64, T_SEQ / 64), 256, 0, stream>>>(
        ctx, Wo_t, bo, x, x2, nullptr, T_SEQ, D_MODEL, D_MODEL);

    ln_kernel<<<T_SEQ, 256, 0, stream>>>(x2, g2, s2, h2);

    // FF1+FF2 fused with SwiGLU epilogue: 128x256 tile (wave 64x128, NI=8)
    mfma_gemm<128, 256, 2, 2, 4, 8, 1><<<dim3(AG_LD / 256, T_SEQ / 128), 256, 0, stream>>>(
        h2, W12_t, b12, nullptr, nullptr, u, T_SEQ, AG_LD, D_MODEL);

    // FF3: [T,3072] @ [3072,768] + b3 + x2   (64x64 tile -> 768 blocks)
    mfma_gemm<64, 64, 2, 2, 2, 2, 0><<<dim3(D_MODEL / 64, T_SEQ / 64), 256, 0, stream>>>(
        u, W3_t, b3, x2, out, nullptr, T_SEQ, D_MODEL, FF_DIM);
}

// Round 11
// 423.238 us; speedup vs baseline: 1.0268x; 1.0268x over previous
//
#include <hip/hip_runtime.h>

#define T_SEQ 4096
#define D_MODEL 768
#define N_HEADS 12
#define HEAD_DIM 64
#define FF_DIM 3072
#define QKV_LD 2304   // 3*D_MODEL
#define AG_LD  6144   // 2*FF_DIM
#define CHUNK 16      // k-tiles per attention block
#define MAXC 4        // max chunks per q-tile (64/16)
#define PSTRIDE 4160  // 64*64 + 64 floats per partial

typedef __bf16 bf16x8 __attribute__((ext_vector_type(8)));
typedef float  f32x4  __attribute__((ext_vector_type(4)));

__device__ __forceinline__ unsigned short f2bf(float f) {
    unsigned int u = __float_as_uint(f);
    u += 0x7FFFu + ((u >> 16) & 1u);
    return (unsigned short)(u >> 16);
}
__device__ __forceinline__ float bf2f(unsigned short s) {
    return __uint_as_float(((unsigned int)s) << 16);
}
__device__ __forceinline__ f32x4 mfma16(bf16x8 a, bf16x8 b, f32x4 c) {
    return __builtin_amdgcn_mfma_f32_16x16x32_bf16(a, b, c, 0, 0, 0);
}
// async global->LDS, 16B per lane; LDS dest = wave-uniform base + lane*16
__device__ __forceinline__ void gload_lds16(const unsigned short* g, unsigned short* l) {
    __builtin_amdgcn_global_load_lds(
        (const __attribute__((address_space(1))) unsigned int*)g,
        (__attribute__((address_space(3))) unsigned int*)l,
        16, 0, 0);
}

// ---------------------------------------------------------------------------
// Fused weight prep: all 7 transposes in one launch. Job table:
//  0..3 : 768x768  ilv=0  (Wq,Wk,Wv -> Wqkv_t @0/768/1536; Wo -> Wo_t @0)
//  4..5 : 768x3072 ilv=1  (w1 -> W12_t off0, w2 -> W12_t off16)
//  6    : 3072x768 ilv=0  (w3 -> W3_t)
// ---------------------------------------------------------------------------
__global__ __launch_bounds__(256) void weight_prep(const float* __restrict__ Wq,
                                                   const float* __restrict__ Wk,
                                                   const float* __restrict__ Wv,
                                                   const float* __restrict__ Wo,
                                                   const float* __restrict__ w1,
                                                   const float* __restrict__ w2,
                                                   const float* __restrict__ w3,
                                                   unsigned short* __restrict__ Wqkv_t,
                                                   unsigned short* __restrict__ Wo_t,
                                                   unsigned short* __restrict__ W12_t,
                                                   unsigned short* __restrict__ W3_t) {
    __shared__ float tile[32][33];
    const int b = blockIdx.x;
    const float* W; unsigned short* Wt;
    int K, N, off, ilv, bx, by;
    if (b < 2304) {                       // jobs 0-3: 576 blocks each (24x24)
        const int j = b / 576, lb = b % 576;
        bx = lb % 24; by = lb / 24;
        K = 768; N = 768; ilv = 0;
        if (j == 0)      { W = Wq; Wt = Wqkv_t; off = 0; }
        else if (j == 1) { W = Wk; Wt = Wqkv_t; off = 768; }
        else if (j == 2) { W = Wv; Wt = Wqkv_t; off = 1536; }
        else             { W = Wo; Wt = Wo_t;   off = 0; }
    } else if (b < 6912) {                // jobs 4-5: 2304 blocks each (96x24)
        const int j = (b - 2304) / 2304, lb = (b - 2304) % 2304;
        bx = lb % 96; by = lb / 96;
        K = 768; N = 3072; ilv = 1;
        W = j ? w2 : w1; Wt = W12_t; off = j ? 16 : 0;
    } else {                              // job 6: 2304 blocks (24x96)
        const int lb = b - 6912;
        bx = lb % 24; by = lb / 24;
        K = 3072; N = 768; ilv = 0;
        W = w3; Wt = W3_t; off = 0;
    }

    const int tx = threadIdx.x & 31, ty = threadIdx.x >> 5;  // 32 x 8
    const int n0 = bx * 32, k0 = by * 32;
    #pragma unroll
    for (int s = 0; s < 32; s += 8)
        tile[ty + s][tx] = W[(size_t)(k0 + ty + s) * N + n0 + tx];
    __syncthreads();
    #pragma unroll
    for (int s = 0; s < 32; s += 8) {
        const int nn = n0 + ty + s;
        const int R = ilv ? ((nn >> 4) * 32 + off + (nn & 15)) : (off + nn);
        Wt[(size_t)R * K + k0 + tx] = f2bf(tile[tx][ty + s]);
    }
}

// interleaved bias pack: o[(n>>4)*32 + (n&15)] = b1[n]; +16 -> b2[n]
__global__ __launch_bounds__(256) void packb12_kernel(const float* __restrict__ b1,
                                                      const float* __restrict__ b2,
                                                      float* __restrict__ o) {
    const int n = blockIdx.x * 256 + threadIdx.x;
    if (n < FF_DIM) {
        o[(n >> 4) * 32 + (n & 15)] = b1[n];
        o[(n >> 4) * 32 + 16 + (n & 15)] = b2[n];
    }
}

// ---------------------------------------------------------------------------
// V transpose (bf16) with per-64-tile KEY-SLOT PERMUTATION:
// Vt[c][t0 + s] = qkv[t0 + kl(s)][1536+c],  kl(s) = (s&3)*16 + (s>>2).
// Matches the P slot assignment s = 4r + ni in softmax_step.
// ---------------------------------------------------------------------------
__global__ __launch_bounds__(256) void vtrans_kernel(const unsigned short* __restrict__ qkv,
                                                     unsigned short* __restrict__ Vt) {
    __shared__ unsigned short tile[64][72];
    const int t0 = blockIdx.x * 64;   // seq
    const int c0 = blockIdx.y * 64;   // feature
    const int tr = threadIdx.x >> 3;         // 0..31
    const int tc = (threadIdx.x & 7) * 8;    // 0,8,..,56
    #pragma unroll
    for (int s = 0; s < 2; ++s) {
        uint4 v = *(const uint4*)(qkv + (size_t)(t0 + tr + s * 32) * QKV_LD + 2 * D_MODEL + c0 + tc);
        *(uint4*)(&tile[tr + s * 32][tc]) = v;
    }
    __syncthreads();
    #pragma unroll
    for (int sb = 0; sb < 2; ++sb) {
        const int cr = tr + sb * 32;
        unsigned short ob[8];
        #pragma unroll
        for (int j = 0; j < 8; ++j) {
            const int s = tc + j;
            ob[j] = tile[(s & 3) * 16 + (s >> 2)][cr];
        }
        *(uint4*)(Vt + (size_t)(c0 + cr) * T_SEQ + t0 + tc) = *(uint4*)ob;
    }
}

// ---------------------------------------------------------------------------
// LayerNorm (fp32 in, bf16 out)
// ---------------------------------------------------------------------------
__global__ __launch_bounds__(256) void ln_kernel(const float* __restrict__ x,
                                                 const float* __restrict__ g,
                                                 const float* __restrict__ b,
                                                 unsigned short* __restrict__ o) {
    const int row = blockIdx.x;
    const float* xr = x + (size_t)row * D_MODEL;
    unsigned short* orow = o + (size_t)row * D_MODEL;
    const int tid = threadIdx.x;

    float v0 = xr[tid], v1 = xr[tid + 256], v2 = xr[tid + 512];
    float sum = v0 + v1 + v2;

    __shared__ float red[4];
    __shared__ float mv[2];
    const int lane = tid & 63, wv = tid >> 6;

    #pragma unroll
    for (int off = 32; off > 0; off >>= 1) sum += __shfl_down(sum, off, 64);
    if (lane == 0) red[wv] = sum;
    __syncthreads();
    if (tid == 0) mv[0] = (red[0] + red[1] + red[2] + red[3]) * (1.0f / D_MODEL);
    __syncthreads();
    const float mean = mv[0];

    float d0 = v0 - mean, d1 = v1 - mean, d2 = v2 - mean;
    float sq = d0 * d0 + d1 * d1 + d2 * d2;
    #pragma unroll
    for (int off = 32; off > 0; off >>= 1) sq += __shfl_down(sq, off, 64);
    if (lane == 0) red[wv] = sq;
    __syncthreads();
    if (tid == 0) mv[1] = (red[0] + red[1] + red[2] + red[3]) * (1.0f / D_MODEL);
    __syncthreads();
    const float rs = rsqrtf(mv[1] + 1e-5f);

    orow[tid]       = f2bf(g[tid]       * d0 * rs + b[tid]);
    orow[tid + 256] = f2bf(g[tid + 256] * d1 * rs + b[tid + 256]);
    orow[tid + 512] = f2bf(g[tid + 512] * d2 * rs + b[tid + 512]);
}

// ---------------------------------------------------------------------------
// bf16 MFMA GEMM, templated tile. BM=WY*MI*16, BN=WX*NI*16, BK=32, 256 thr,
// async global_load_lds staging, double-buffered, one barrier per iter.
// Chunk c (16B) holds X[(c>>6)*16 + (c&15)][((c>>4)&3)*8..+8].
// EPI=0: C = acc + bias + res -> Cf (fp32) or Cb (bf16), pitch N.
// EPI=1: SwiGLU epilogue on 16-col-interleaved B: u = silu(a+ba)*(g+bg),
//        -> Cb, pitch N/2.
// ---------------------------------------------------------------------------
template<int BM, int BN, int WY, int WX, int MI, int NI, int EPI>
__global__ __launch_bounds__(256) void mfma_gemm(const unsigned short* __restrict__ A,
                                                 const unsigned short* __restrict__ Bt,
                                                 const float* __restrict__ bias,
                                                 const float* __restrict__ res,
                                                 float* __restrict__ Cf,
                                                 unsigned short* __restrict__ Cb,
                                                 int M, int N, int K) {
    constexpr int CA = BM * 4;            // A chunks
    constexpr int CT = BM * 4 + BN * 4;   // total chunks
    constexpr int SA = CA / 256;          // DMA steps covering A
    constexpr int ST = CT / 256;          // total DMA steps
    __shared__ unsigned short S[2][CT * 8];

    const int t = threadIdx.x;
    const int bn = blockIdx.x * BN;
    const int bm = blockIdx.y * BM;
    const int w = t >> 6, lane = t & 63;
    const int wy = w / WX, wx = w % WX;
    const int quad = lane >> 4, r = lane & 15;
    const int rc = lane & 15, kq = (lane >> 4) & 3;

    const unsigned short* gp[ST];
    #pragma unroll
    for (int s = 0; s < ST; ++s) {
        if (s < SA) gp[s] = A  + (size_t)(bm + (s * 4 + w) * 16 + rc) * K + kq * 8;
        else        gp[s] = Bt + (size_t)(bn + ((s - SA) * 4 + w) * 16 + rc) * K + kq * 8;
    }

    f32x4 acc[MI][NI];
    const f32x4 fz = {0.f, 0.f, 0.f, 0.f};
    #pragma unroll
    for (int i = 0; i < MI; ++i)
        #pragma unroll
        for (int j = 0; j < NI; ++j) acc[i][j] = fz;

    // prologue: stage k-block 0 into buf 0
    #pragma unroll
    for (int s = 0; s < ST; ++s)
        gload_lds16(gp[s], &S[0][(s * 256 + w * 64) * 8]);

    const int niter = K >> 5;
    for (int it = 0; it < niter; ++it) {
        const int buf = it & 1;
        __syncthreads();            // drains vmcnt: buf's DMA complete; prior reads done
        if (it + 1 < niter) {
            const int ko = (it + 1) * 32;
            #pragma unroll
            for (int s = 0; s < ST; ++s)
                gload_lds16(gp[s] + ko, &S[buf ^ 1][(s * 256 + w * 64) * 8]);
        }

        bf16x8 af[MI], bfr[NI];
        #pragma unroll
        for (int mi = 0; mi < MI; ++mi)
            af[mi] = *(const bf16x8*)(&S[buf][((wy * MI + mi) * 64 + lane) * 8]);
        #pragma unroll
        for (int ni = 0; ni < NI; ++ni)
            bfr[ni] = *(const bf16x8*)(&S[buf][(CA + (wx * NI + ni) * 64 + lane) * 8]);
        #pragma unroll
        for (int mi = 0; mi < MI; ++mi)
            #pragma unroll
            for (int ni = 0; ni < NI; ++ni)
                acc[mi][ni] = mfma16(af[mi], bfr[ni], acc[mi][ni]);
    }

    float bv[NI];
    #pragma unroll
    for (int ni = 0; ni < NI; ++ni)
        bv[ni] = bias ? bias[bn + (wx * NI + ni) * 16 + r] : 0.0f;

    if (EPI == 0) {
        #pragma unroll
        for (int mi = 0; mi < MI; ++mi) {
            #pragma unroll
            for (int i = 0; i < 4; ++i) {
                const int m = bm + (wy * MI + mi) * 16 + quad * 4 + i;
                #pragma unroll
                for (int ni = 0; ni < NI; ++ni) {
                    const int n = bn + (wx * NI + ni) * 16 + r;
                    float v = acc[mi][ni][i] + bv[ni];
                    if (res) v += res[(size_t)m * N + n];
                    if (Cf) Cf[(size_t)m * N + n] = v;
                    else    Cb[(size_t)m * N + n] = f2bf(v);
                }
            }
        }
    } else {
        // SwiGLU: ni pairs (2p, 2p+1) = (a-block, g-block), same lane r
        #pragma unroll
        for (int mi = 0; mi < MI; ++mi) {
            #pragma unroll
            for (int i = 0; i < 4; ++i) {
                const int m = bm + (wy * MI + mi) * 16 + quad * 4 + i;
                #pragma unroll
                for (int p = 0; p < NI / 2; ++p) {
                    float a = acc[mi][2 * p][i] + bv[2 * p];
                    float g = acc[mi][2 * p + 1][i] + bv[2 * p + 1];
                    float uu = a / (1.0f + __expf(-a)) * g;
                    const int n = (bn >> 1) + wx * (NI / 2) * 16 + p * 16 + r;
                    Cb[(size_t)m * (N >> 1) + n] = f2bf(uu);
                }
            }
        }
    }
}

// ---------------------------------------------------------------------------
// Softmax step, fixed-max: p = exp(s) (scale folded into Q), masked -> 0.
// P keys {r,16+r,32+r,48+r} -> 4 consecutive shorts (one b64 write) at
// logical chunk (ks=r>>3, kq=(r>>1)&3, rr=quad*4+i), j0=4*(r&1).
// PHYSICAL chunk row is XOR-swizzled: rr_phys = rr ^ (r>>1), which sweeps
// all 32 banks across the 8 (ks,kq) combos -> conflict-free b64 writes.
// PV read applies the same involutive swizzle. V is staged with the matching
// key permutation kl(s) = (s&3)*16 + (s>>2) (vtrans).
// ---------------------------------------------------------------------------
template <bool DIAG>
__device__ __forceinline__ void softmax_step(const f32x4 sacc[4],
                                             unsigned short* __restrict__ Pw,
                                             int k0, int qg_base, int r, int quad) {
    const int rp = r >> 1;                                    // = ks*4 + kq
    const int cbase = (r >> 3) * 64 + ((r >> 1) & 3) * 16;
    #pragma unroll
    for (int i = 0; i < 4; ++i) {
        unsigned int pk[2];
        #pragma unroll
        for (int ni = 0; ni < 4; ++ni) {
            float p = __expf(sacc[ni][i]);
            if (DIAG) { if (k0 + ni * 16 + r > qg_base + i) p = 0.0f; }
            const unsigned int pb = (__float_as_uint(p) + 0x8000u) >> 16;  // fast RN
            if (ni & 1) pk[ni >> 1] |= pb << 16;
            else        pk[ni >> 1] = pb;
        }
        const int rrp = (quad * 4 + i) ^ rp;                  // bank swizzle
        uint2 wv; wv.x = pk[0]; wv.y = pk[1];
        *(uint2*)(&Pw[(cbase + rrp) * 8 + 4 * (r & 1)]) = wv;
    }
}

// ---------------------------------------------------------------------------
// Flash attention partial, bf16 MFMA, fixed-max softmax, K-SPLIT.
// Block = (64 q-rows, head, k-chunk of <=16 k-tiles). Partial O (fp32 64x64)
// and l (fp32 64) per chunk to workspace; additive across chunks.
// ---------------------------------------------------------------------------
__global__ __launch_bounds__(256) void attn_partial(const unsigned short* __restrict__ qkv,
                                                    const unsigned short* __restrict__ Vt,
                                                    float* __restrict__ part) {
    const int h = blockIdx.y;
    // decode blockIdx.x -> (qt, ci), longest q-tiles first
    int b = (int)blockIdx.x, qt = 63, ci = 0;
    for (int q = 63; q >= 0; --q) {
        const int nc = (q >> 4) + 1;       // ceil((q+1)/16)
        if (b < nc) { qt = q; ci = b; break; }
        b -= nc;
    }
    const int q0 = qt * 64;
    const int kb = ci * CHUNK;             // first k-tile of this chunk
    const int nt = min(CHUNK, qt + 1 - kb);

    const int t = threadIdx.x;
    const int w = t >> 6, lane = t & 63;
    const int quad = lane >> 4, r = lane & 15;

    __shared__ unsigned short Ks[2][4096];
    __shared__ unsigned short Vs[2][4096];
    __shared__ unsigned short Ps[4][1024];

    // Q fragments, scale 1/8 folded in (exact power of 2)
    bf16x8 aq[2];
    {
        const unsigned short* qp = qkv + (size_t)(q0 + w * 16 + r) * QKV_LD + h * 64 + quad * 8;
        uint4 q0v = *(const uint4*)(qp);
        uint4 q1v = *(const uint4*)(qp + 32);
        const unsigned short* p0 = (const unsigned short*)&q0v;
        const unsigned short* p1 = (const unsigned short*)&q1v;
        #pragma unroll
        for (int j = 0; j < 8; ++j) {
            aq[0][j] = (__bf16)(bf2f(p0[j]) * 0.125f);
            aq[1][j] = (__bf16)(bf2f(p1[j]) * 0.125f);
        }
    }

    bf16x8 ones;
    #pragma unroll
    for (int j = 0; j < 8; ++j) ones[j] = (__bf16)1.0f;

    // per-lane staging sources (chunk c = s*256 + w*64 + lane), offset by kb
    const int rc = lane & 15, qc = (lane >> 4) & 3;
    const unsigned short* kg0 = qkv + (size_t)(kb * 64 + w * 16 + rc) * QKV_LD + D_MODEL + h * 64 + qc * 8;
    const unsigned short* kg1 = kg0 + 32;
    const unsigned short* vg0 = Vt + (size_t)(h * 64 + w * 16 + rc) * T_SEQ + kb * 64 + qc * 8;
    const unsigned short* vg1 = vg0 + 32;
    const int l0 = (w * 64) * 8, l1 = (256 + w * 64) * 8;

    const f32x4 fz = {0.f, 0.f, 0.f, 0.f};
    f32x4 acc_o[4] = {fz, fz, fz, fz};
    f32x4 acc_l = fz;
    const int qg_base = q0 + w * 16 + quad * 4;

    // prologue: stage first tile into buf 0
    gload_lds16(kg0, &Ks[0][l0]);
    gload_lds16(kg1, &Ks[0][l1]);
    gload_lds16(vg0, &Vs[0][l0]);
    gload_lds16(vg1, &Vs[0][l1]);

    for (int lt = 0; lt < nt; ++lt) {
        const int kt = kb + lt;
        const int buf = lt & 1;
        __syncthreads();            // DMA for buf complete; prior reads done
        if (lt + 1 < nt) {
            const size_t kofs = (size_t)(lt + 1) * 64;
            gload_lds16(kg0 + kofs * QKV_LD, &Ks[buf ^ 1][l0]);
            gload_lds16(kg1 + kofs * QKV_LD, &Ks[buf ^ 1][l1]);
            gload_lds16(vg0 + kofs, &Vs[buf ^ 1][l0]);
            gload_lds16(vg1 + kofs, &Vs[buf ^ 1][l1]);
        }

        // S = (Q/8) @ K^T
        f32x4 sacc[4] = {fz, fz, fz, fz};
        #pragma unroll
        for (int ks = 0; ks < 2; ++ks)
            #pragma unroll
            for (int ni = 0; ni < 4; ++ni) {
                bf16x8 bk = *(const bf16x8*)(&Ks[buf][((ks * 4 + ni) * 64 + lane) * 8]);
                sacc[ni] = mfma16(aq[ks], bk, sacc[ni]);
            }

        const int k0 = kt * 64;
        if (kt == qt)
            softmax_step<true >(sacc, Ps[w], k0, qg_base, r, quad);
        else
            softmax_step<false>(sacc, Ps[w], k0, qg_base, r, quad);

        // O += P @ V ; l += P @ 1   (P per-wave; lgkm ordering suffices)
        const int kqr = lane >> 4, rrr = lane & 15;
        #pragma unroll
        for (int ks = 0; ks < 2; ++ks) {
            // physical chunk with the involutive XOR swizzle
            const int pc = ks * 64 + kqr * 16 + (rrr ^ (ks * 4 + kqr));
            bf16x8 ap = *(const bf16x8*)(&Ps[w][pc * 8]);
            #pragma unroll
            for (int nd = 0; nd < 4; ++nd) {
                bf16x8 bv = *(const bf16x8*)(&Vs[buf][((ks * 4 + nd) * 64 + lane) * 8]);
                acc_o[nd] = mfma16(ap, bv, acc_o[nd]);
            }
            acc_l = mfma16(ap, ones, acc_l);
        }
    }

    // write fp32 partial: O[64][64] then l[64]
    float* pb = part + ((size_t)(qt * N_HEADS + h) * MAXC + ci) * PSTRIDE;
    #pragma unroll
    for (int i = 0; i < 4; ++i) {
        const int row = w * 16 + quad * 4 + i;
        #pragma unroll
        for (int nd = 0; nd < 4; ++nd)
            pb[row * 64 + nd * 16 + r] = acc_o[nd][i];
        if (r == 0) pb[4096 + row] = acc_l[i];   // all 16 cols of acc_l equal
    }
}

// ---------------------------------------------------------------------------
// Merge partials: ctx[q0+row][h*64+c] = (sum_ci O_ci[row][c]) / (sum_ci l_ci[row])
// ---------------------------------------------------------------------------
__global__ __launch_bounds__(256) void attn_merge(const float* __restrict__ part,
                                                  unsigned short* __restrict__ ctx) {
    const int qt = blockIdx.x, h = blockIdx.y;
    const int nc = (qt >> 4) + 1;
    const int t = threadIdx.x;
    const int row = t >> 2, cg = (t & 3) * 16;

    float o[16];
    #pragma unroll
    for (int j = 0; j < 16; ++j) o[j] = 0.0f;
    float l = 0.0f;

    for (int ci = 0; ci < nc; ++ci) {
        const float* pb = part + ((size_t)(qt * N_HEADS + h) * MAXC + ci) * PSTRIDE;
        l += pb[4096 + row];
        #pragma unroll
        for (int j = 0; j < 16; j += 4) {
            float4 v = *(const float4*)(pb + row * 64 + cg + j);
            o[j] += v.x; o[j + 1] += v.y; o[j + 2] += v.z; o[j + 3] += v.w;
        }
    }
    const float inv = 1.0f / l;
    unsigned short ob[16];
    #pragma unroll
    for (int j = 0; j < 16; ++j) ob[j] = f2bf(o[j] * inv);
    unsigned short* dst = ctx + (size_t)(qt * 64 + row) * D_MODEL + h * 64 + cg;
    *(uint4*)(dst) = *(uint4*)(ob);
    *(uint4*)(dst + 8) = *(uint4*)(ob + 8);
}

// ---------------------------------------------------------------------------
// launch
// ---------------------------------------------------------------------------
extern "C" void kernel_launch(void* const* d_in, const int* in_sizes, int n_in,
                              void* d_out, int out_size, void* d_ws, size_t ws_size,
                              hipStream_t stream) {
    const float* x  = (const float*)d_in[0];
    const float* Wq = (const float*)d_in[1];
    const float* Wk = (const float*)d_in[2];
    const float* Wv = (const float*)d_in[3];
    const float* Wo = (const float*)d_in[4];
    const float* bo = (const float*)d_in[5];
    const float* w1 = (const float*)d_in[6];
    const float* b1 = (const float*)d_in[7];
    const float* w2 = (const float*)d_in[8];
    const float* b2 = (const float*)d_in[9];
    const float* w3 = (const float*)d_in[10];
    const float* b3 = (const float*)d_in[11];
    const float* g1 = (const float*)d_in[12];
    const float* s1 = (const float*)d_in[13];
    const float* g2 = (const float*)d_in[14];
    const float* s2 = (const float*)d_in[15];
    float* out = (float*)d_out;

    const size_t TD = (size_t)T_SEQ * D_MODEL;

    char* p = (char*)d_ws;
    auto alloc = [&](size_t bytes) { char* r = p; p += (bytes + 255) & ~(size_t)255; return r; };
    unsigned short* h      = (unsigned short*)alloc(TD * 2);
    unsigned short* qkv    = (unsigned short*)alloc((size_t)T_SEQ * QKV_LD * 2);
    unsigned short* Vtb    = (unsigned short*)alloc((size_t)D_MODEL * T_SEQ * 2);
    unsigned short* ctx    = (unsigned short*)alloc(TD * 2);
    float*          x2     = (float*)alloc(TD * 4);
    unsigned short* h2     = (unsigned short*)alloc(TD * 2);
    unsigned short* u      = (unsigned short*)alloc((size_t)T_SEQ * FF_DIM * 2);
    unsigned short* Wqkv_t = (unsigned short*)alloc((size_t)QKV_LD * D_MODEL * 2);
    unsigned short* Wo_t   = (unsigned short*)alloc((size_t)D_MODEL * D_MODEL * 2);
    unsigned short* W12_t  = (unsigned short*)alloc((size_t)AG_LD * D_MODEL * 2);
    unsigned short* W3_t   = (unsigned short*)alloc((size_t)D_MODEL * FF_DIM * 2);
    float*          b12    = (float*)alloc((size_t)AG_LD * 4);
    float*          part   = (float*)alloc((size_t)64 * N_HEADS * MAXC * PSTRIDE * 4);

    // --- weight prep (single fused launch + bias pack) ---
    weight_prep<<<9216, 256, 0, stream>>>(Wq, Wk, Wv, Wo, w1, w2, w3,
                                          Wqkv_t, Wo_t, W12_t, W3_t);
    packb12_kernel<<<12, 256, 0, stream>>>(b1, b2, b12);

    // --- block ---
    ln_kernel<<<T_SEQ, 256, 0, stream>>>(x, g1, s1, h);

    // QKV: [T,768] @ [768,2304]
    mfma_gemm<128, 128, 2, 2, 4, 4, 0><<<dim3(QKV_LD / 128, T_SEQ / 128), 256, 0, stream>>>(
        h, Wqkv_t, nullptr, nullptr, nullptr, qkv, T_SEQ, QKV_LD, D_MODEL);

    vtrans_kernel<<<dim3(T_SEQ / 64, D_MODEL / 64), 256, 0, stream>>>(qkv, Vtb);

    // attention: 160 chunks/head, partials + merge
    attn_partial<<<dim3(160, N_HEADS), 256, 0, stream>>>(qkv, Vtb, part);
    attn_merge<<<dim3(T_SEQ / 64, N_HEADS), 256, 0, stream>>>(part, ctx);

    // Wo: [T,768] @ [768,768] + bo + x   (64x64 tile -> 768 blocks)
    mfma_gemm<64, 64, 2, 2, 2, 2, 0><<<dim3(D_MODEL / 64, T_SEQ / 64), 256, 0, stream>>>(
        ctx, Wo_t, bo, x, x2, nullptr, T_SEQ, D_MODEL, D_MODEL);

    ln_kernel<<<T_SEQ, 256, 0, stream>>>(x2, g2, s2, h2);

    // FF1+FF2 fused with SwiGLU epilogue: 128x256 tile (wave 64x128, NI=8)
    mfma_gemm<128, 256, 2, 2, 4, 8, 1><<<dim3(AG_LD / 256, T_SEQ / 128), 256, 0, stream>>>(
        h2, W12_t, b12, nullptr, nullptr, u, T_SEQ, AG_LD, D_MODEL);

    // FF3: [T,3072] @ [3072,768] + b3 + x2   (64x64 tile -> 768 blocks)
    mfma_gemm<64, 64, 2, 2, 2, 2, 0><<<dim3(D_MODEL / 64, T_SEQ / 64), 256, 0, stream>>>(
        u, W3_t, b3, x2, out, nullptr, T_SEQ, D_MODEL, FF_DIM);
}